// Round 7
// baseline (889.268 us; speedup 1.0000x reference)
//
#include <hip/hip_runtime.h>
#include <hip/hip_bf16.h>
#include <math.h>

#define CC 120       // channels
#define NHEADS 6
#define HDIM 20      // head dim
#define NTOK 128     // tokens per window
#define HID2 240
#define SCALE_F 0.2236067977499790f  // 20^-0.5

typedef __hip_bfloat16 bf16;
typedef __attribute__((ext_vector_type(8))) short bf16x8;   // 8 bf16 (4 VGPRs)
typedef __attribute__((ext_vector_type(4))) float f32x4;    // MFMA accumulator

__device__ inline f32x4 mfma16(bf16x8 a, bf16x8 b, f32x4 c) {
  return __builtin_amdgcn_mfma_f32_16x16x32_bf16(a, b, c, 0, 0, 0);
}

__device__ inline short f2bf_s(float f) {
  bf16 h = __float2bfloat16(f);
  return *reinterpret_cast<short*>(&h);
}

// ---------------------------------------------------------------------------
// token -> rolled spatial source position (also the scatter destination for
// window-reverse + un-roll, which is the same map).
__device__ inline size_t token_src_offset(int token) {
  const int wi = token >> 7, n = token & 127;
  const int b_ = wi >> 8, rem = wi & 255;
  const int dB = rem >> 6, hB = (rem >> 3) & 7, wB = rem & 7;
  const int dI = n >> 6, hI = (n >> 3) & 7, wI = n & 7;
  const int d = dB * 2 + dI, h = hB * 8 + hI, w = wB * 8 + wI;
  const int ds = (d + 1) & 7, hs = (h + 4) & 63, ws2 = (w + 4) & 63;
  return (((size_t)(b_ * 8 + ds) * 64 + hs) * 64 + ws2) * CC;
}

__device__ inline void ln120(float* xv, const float* __restrict__ g,
                             const float* __restrict__ bb) {
  float s0 = 0.f, s1 = 0.f, s2 = 0.f, s3 = 0.f;
#pragma unroll
  for (int k = 0; k < CC; k += 4) {
    s0 += xv[k]; s1 += xv[k + 1]; s2 += xv[k + 2]; s3 += xv[k + 3];
  }
  const float mean = ((s0 + s1) + (s2 + s3)) * (1.f / 120.f);
  float v0 = 0.f, v1 = 0.f, v2 = 0.f, v3 = 0.f;
#pragma unroll
  for (int k = 0; k < CC; k += 4) {
    float d0 = xv[k] - mean, d1 = xv[k + 1] - mean;
    float d2 = xv[k + 2] - mean, d3 = xv[k + 3] - mean;
    v0 += d0 * d0; v1 += d1 * d1; v2 += d2 * d2; v3 += d3 * d3;
  }
  const float rstd = rsqrtf(((v0 + v1) + (v2 + v3)) * (1.f / 120.f) + 1e-5f);
#pragma unroll
  for (int k = 0; k < CC; k++) xv[k] = (xv[k] - mean) * rstd * g[k] + bb[k];
}

__device__ inline float dot120(const float* xv, const float* __restrict__ wr) {
  float a0 = 0.f, a1 = 0.f, a2 = 0.f, a3 = 0.f;
#pragma unroll
  for (int k = 0; k < CC; k += 4) {
    a0 = fmaf(xv[k], wr[k], a0);
    a1 = fmaf(xv[k + 1], wr[k + 1], a1);
    a2 = fmaf(xv[k + 2], wr[k + 2], a2);
    a3 = fmaf(xv[k + 3], wr[k + 3], a3);
  }
  return (a0 + a1) + (a2 + a3);
}

// ===========================================================================
// FAST PATH
// ===========================================================================
// Weight prep.
//  Bffn [512][128]: rows 0..239 = W11, 256..495 = W12 (K pad, bias separate)
//  Bfc2 [128][256], Bproj [128][256]
//  Wself2/Wmut2 [576][128]: rows 0..191 q (heads padded to 32, SCALE folded),
//    192..383 k, 384..575 v. col 120 = bias (A1 col120 == 1), pads 0.
//    v-row pad chan 20 = e120 (=> V col 20 == 1.0: PV computes softmax rowsum).
__global__ __launch_bounds__(256) void k_prep(
    const float* __restrict__ w11, const float* __restrict__ w12,
    const float* __restrict__ fc2w, const float* __restrict__ projw,
    const float* __restrict__ wself, const float* __restrict__ bself,
    const float* __restrict__ wmut, const float* __restrict__ bmut,
    bf16* __restrict__ Bffn, bf16* __restrict__ Bfc2, bf16* __restrict__ Bproj,
    bf16* __restrict__ Wself2, bf16* __restrict__ Wmut2) {
  const int i = blockIdx.x * 256 + threadIdx.x;
  if (i < 65536) {
    const int r = i >> 7, k = i & 127;
    float v = 0.f;
    if (k < 120) {
      if (r < 240) v = w11[r * 120 + k];
      else if (r >= 256 && r < 496) v = w12[(r - 256) * 120 + k];
    }
    Bffn[i] = __float2bfloat16(v);
  } else if (i < 98304) {
    const int j = i - 65536, r = j >> 8, k = j & 255;
    Bfc2[j] = __float2bfloat16((r < 120 && k < 240) ? fc2w[r * 240 + k] : 0.f);
  } else if (i < 131072) {
    const int j = i - 98304, r = j >> 8, k = j & 255;
    Bproj[j] = __float2bfloat16((r < 120 && k < 240) ? projw[r * 240 + k] : 0.f);
  } else if (i < 278528) {
    const int j = (i - 131072) % 73728;
    const bool is_self = (i - 131072) < 73728;
    const float* w = is_self ? wself : wmut;
    const float* b = is_self ? bself : bmut;
    const int r = j >> 7, k = j & 127;
    const int grp = r / 192;              // 0=q 1=k 2=v
    const int rr = r % 192;
    const int hh = rr >> 5, jj = rr & 31;
    float v = 0.f;
    if (jj < 20) {
      const int orow = grp * 120 + hh * 20 + jj;
      if (k < 120) v = w[orow * 120 + k];
      else if (k == 120) v = b[orow];
      if (grp == 0) v *= SCALE_F;
    } else if (grp == 2 && jj == 20 && k == 120) {
      v = 1.0f;                           // rowsum column
    }
    (is_self ? Wself2 : Wmut2)[j] = __float2bfloat16(v);
  }
}

// posq2[t63][c] = dot(pos[t63], W'_c over real channels); SCALE on q cols.
__global__ __launch_bounds__(256) void k_posq2(
    const float* __restrict__ pos, const float* __restrict__ wmut,
    float* __restrict__ posq) {
  const int i = blockIdx.x * 256 + threadIdx.x;
  if (i >= 64 * 576) return;
  const int t63 = i / 576, c = i % 576;
  const int grp = c / 192, rr = c % 192;
  const int hh = rr >> 5, jj = rr & 31;
  float v = 0.f;
  if (jj < 20) {
    v = dot120(pos + (size_t)t63 * CC, wmut + (size_t)(grp * 120 + hh * 20 + jj) * CC);
    if (grp == 0) v *= SCALE_F;
  }
  posq[i] = v;
}

// biasC[h][row][col] = rpb[rpi[row,col]*6+h]  (de-gathered rel-pos bias, fp32)
__global__ __launch_bounds__(256) void k_biasc(
    const int* __restrict__ rpi, const float* __restrict__ rpb,
    float* __restrict__ biasC) {
  const int i = blockIdx.x * 256 + threadIdx.x;
  if (i >= NHEADS * 16384) return;
  const int h = i >> 14, rc = i & 16383;
  biasC[i] = rpb[rpi[rc] * NHEADS + h];
}

// LN1 + roll + partition -> A1 bf16 [131072][128], col 120 = 1.0 (bias col).
// float4 row loads (rows are 480 B, 16B-aligned) + bf16x8 16B stores.
__global__ __launch_bounds__(256) void k_a1(
    const float* __restrict__ x, const float* __restrict__ g1,
    const float* __restrict__ b1, bf16* __restrict__ A1) {
  const int token = blockIdx.x * 256 + threadIdx.x;
  const float4* xr4 = (const float4*)(x + token_src_offset(token));
  float xv[CC];
#pragma unroll
  for (int k = 0; k < 30; k++) {
    const float4 v = xr4[k];
    xv[k * 4] = v.x; xv[k * 4 + 1] = v.y; xv[k * 4 + 2] = v.z; xv[k * 4 + 3] = v.w;
  }
  ln120(xv, g1, b1);
  bf16x8* dst8 = (bf16x8*)(A1 + (size_t)token * 128);
#pragma unroll
  for (int k = 0; k < 15; k++) {
    bf16x8 v;
#pragma unroll
    for (int j = 0; j < 8; j++) v[j] = f2bf_s(xv[k * 8 + j]);
    dst8[k] = v;
  }
  bf16x8 tail = {0, 0, 0, 0, 0, 0, 0, 0};
  tail[0] = f2bf_s(1.0f);
  dst8[15] = tail;
}

// QKV GEMM for a 32768-token chunk. N=576 (36 tiles, 18 pairs), K=128.
// q/k -> qkA [32768][384]; v -> vt [256win][6][32 vchan][128 key] (transposed).
template <bool MUT>
__global__ __launch_bounds__(64) void k_qkv2(
    const bf16* __restrict__ A1, const bf16* __restrict__ W2,
    const float* __restrict__ posq, bf16* __restrict__ qkA,
    bf16* __restrict__ vt, int tokbase) {
  const int pair = blockIdx.x;           // 0..17
  const int lane = threadIdx.x;
  const int ln = lane & 15, quad = lane >> 4;
  bf16x8 bfr[2][4];
#pragma unroll
  for (int nt = 0; nt < 2; nt++)
#pragma unroll
    for (int s = 0; s < 4; s++)
      bfr[nt][s] = *(const bf16x8*)(W2 + (size_t)((pair * 2 + nt) * 16 + ln) * 128 + s * 32 + quad * 8);
  const int m0 = blockIdx.y * 64;        // local row in chunk
  for (int it = 0; it < 2; it++) {
    const int m = m0 + it * 32;
    f32x4 acc[2][2] = {};
    bf16x8 af[2][4];
#pragma unroll
    for (int mi = 0; mi < 2; mi++)
#pragma unroll
      for (int s = 0; s < 4; s++)
        af[mi][s] = *(const bf16x8*)(A1 + (size_t)(tokbase + m + mi * 16 + ln) * 128 + s * 32 + quad * 8);
#pragma unroll
    for (int s = 0; s < 4; s++)
#pragma unroll
      for (int mi = 0; mi < 2; mi++)
#pragma unroll
        for (int nt = 0; nt < 2; nt++)
          acc[mi][nt] = mfma16(af[mi][s], bfr[nt][s], acc[mi][nt]);
#pragma unroll
    for (int mi = 0; mi < 2; mi++)
#pragma unroll
      for (int nt = 0; nt < 2; nt++) {
        const int col = (pair * 2 + nt) * 16 + ln;
#pragma unroll
        for (int r = 0; r < 4; r++) {
          const int rloc = m + mi * 16 + quad * 4 + r;
          float v = acc[mi][nt][r];
          if (MUT) v += posq[((tokbase + rloc) & 63) * 576 + col];
          if (col < 384) {
            qkA[(size_t)rloc * 384 + col] = __float2bfloat16(v);
          } else {
            const int cc2 = col - 384, hd = cc2 >> 5, vc = cc2 & 31;
            vt[((size_t)(rloc >> 7) * 6 + hd) * 4096 + vc * 128 + (rloc & 127)] =
                __float2bfloat16(v);
          }
        }
      }
  }
}

// MFMA self-attention, 4 waves/block: wave w owns query rows [w*32, w*32+32)
// of its (window, head). biasC is the pre-gathered rel-pos bias.
__global__ __launch_bounds__(256) void k_attn_self4(
    const bf16* __restrict__ qkA, const bf16* __restrict__ vt,
    const float* __restrict__ mask, const float* __restrict__ biasC,
    bf16* __restrict__ xout, int tokbase) {
  __shared__ bf16 P[128 * 40];
  const int wiL = blockIdx.x, hh = blockIdx.y;
  const int w = threadIdx.x >> 6, lane = threadIdx.x & 63;
  const int ln = lane & 15, quad = lane >> 4;
  const bf16* qbase = qkA + (size_t)wiL * NTOK * 384 + hh * 32 + quad * 8;
  const bf16* kbase = qbase + 192;
  const bf16* vbase = vt + ((size_t)wiL * 6 + hh) * 4096;
  const float* mbase = mask + (size_t)wiL * 16384;
  const float* bbase = biasC + hh * 16384;
  bf16x8 qf[2];
#pragma unroll
  for (int i = 0; i < 2; i++)
    qf[i] = *(const bf16x8*)(qbase + (size_t)((w * 2 + i) * 16 + ln) * 384);
  f32x4 accO[2][2];
#pragma unroll
  for (int i = 0; i < 2; i++)
#pragma unroll
    for (int nt = 0; nt < 2; nt++) accO[i][nt] = (f32x4){0.f, 0.f, 0.f, 0.f};

  for (int chunk = 0; chunk < 4; chunk++) {
    bf16x8 kf[2], vf[2];
    kf[0] = *(const bf16x8*)(kbase + (size_t)(chunk * 32 + ln) * 384);
    kf[1] = *(const bf16x8*)(kbase + (size_t)(chunk * 32 + 16 + ln) * 384);
    vf[0] = *(const bf16x8*)(vbase + ln * 128 + chunk * 32 + quad * 8);
    vf[1] = *(const bf16x8*)(vbase + (16 + ln) * 128 + chunk * 32 + quad * 8);
#pragma unroll
    for (int i = 0; i < 2; i++) {
      f32x4 s0 = mfma16(qf[i], kf[0], (f32x4){0.f, 0.f, 0.f, 0.f});
      f32x4 s1 = mfma16(qf[i], kf[1], (f32x4){0.f, 0.f, 0.f, 0.f});
#pragma unroll
      for (int r = 0; r < 4; r++) {
        const int row = w * 32 + i * 16 + quad * 4 + r;
        const int c0 = chunk * 32 + ln, c1 = c0 + 16;
        const float b0 = bbase[row * 128 + c0] + mbase[row * 128 + c0];
        const float b1 = bbase[row * 128 + c1] + mbase[row * 128 + c1];
        P[row * 40 + ln] = __float2bfloat16(__expf(s0[r] + b0));
        P[row * 40 + 16 + ln] = __float2bfloat16(__expf(s1[r] + b1));
      }
    }
    __syncthreads();
#pragma unroll
    for (int i = 0; i < 2; i++) {
      bf16x8 pf = *(const bf16x8*)(&P[(w * 32 + i * 16 + ln) * 40 + quad * 8]);
      accO[i][0] = mfma16(pf, vf[0], accO[i][0]);
      accO[i][1] = mfma16(pf, vf[1], accO[i][1]);
    }
    __syncthreads();
  }
#pragma unroll
  for (int i = 0; i < 2; i++) {
#pragma unroll
    for (int r = 0; r < 4; r++) {
      const float rs = __shfl(accO[i][1][r], (lane & 48) + 4, 64);
      const float inv = 1.f / rs;
      const int row = w * 32 + i * 16 + quad * 4 + r;
      const int token = tokbase + wiL * NTOK + row;
      bf16* orow = xout + (size_t)token * 256 + CC + hh * HDIM;
      orow[ln] = __float2bfloat16(accO[i][0][r] * inv);
      if (ln < 4) orow[16 + ln] = __float2bfloat16(accO[i][1][r] * inv);
    }
  }
}

// MFMA mutual attention, 4 waves/block: wave w owns query rows [w*32,w*32+32).
// waves 0,1 (q rows 0..63) = x2: keys 64..127, out rows 64..127
// waves 2,3 (q rows 64..127) = x1: keys 0..63,  out rows 0..63
__global__ __launch_bounds__(256) void k_attn_mut4(
    const bf16* __restrict__ qkA, const bf16* __restrict__ vt,
    const float* __restrict__ mask, bf16* __restrict__ xout, int tokbase) {
  __shared__ bf16 P[128 * 40];
  const int wiL = blockIdx.x, hh = blockIdx.y;
  const int w = threadIdx.x >> 6, lane = threadIdx.x & 63;
  const int ln = lane & 15, quad = lane >> 4;
  const bf16* qbase = qkA + (size_t)wiL * NTOK * 384 + hh * 32 + quad * 8;
  const bf16* kbase = qbase + 192;
  const bf16* vbase = vt + ((size_t)wiL * 6 + hh) * 4096;
  const float* mbase = mask + (size_t)wiL * 16384;
  const int kb = (w < 2) ? 64 : 0;
  bf16x8 qf[2];
#pragma unroll
  for (int i = 0; i < 2; i++)
    qf[i] = *(const bf16x8*)(qbase + (size_t)((w * 2 + i) * 16 + ln) * 384);
  f32x4 accO[2][2];
#pragma unroll
  for (int i = 0; i < 2; i++)
#pragma unroll
    for (int nt = 0; nt < 2; nt++) accO[i][nt] = (f32x4){0.f, 0.f, 0.f, 0.f};

  for (int chunk = 0; chunk < 2; chunk++) {
    const int key0 = kb + chunk * 32;
    bf16x8 kf[2], vf[2];
    kf[0] = *(const bf16x8*)(kbase + (size_t)(key0 + ln) * 384);
    kf[1] = *(const bf16x8*)(kbase + (size_t)(key0 + 16 + ln) * 384);
    vf[0] = *(const bf16x8*)(vbase + ln * 128 + key0 + quad * 8);
    vf[1] = *(const bf16x8*)(vbase + (16 + ln) * 128 + key0 + quad * 8);
#pragma unroll
    for (int i = 0; i < 2; i++) {
      f32x4 s0 = mfma16(qf[i], kf[0], (f32x4){0.f, 0.f, 0.f, 0.f});
      f32x4 s1 = mfma16(qf[i], kf[1], (f32x4){0.f, 0.f, 0.f, 0.f});
#pragma unroll
      for (int r = 0; r < 4; r++) {
        const int row = w * 32 + i * 16 + quad * 4 + r;   // global query row
        const int mrow = row & 63;                        // mask row (0..63)
        const int c0 = chunk * 32 + ln, c1 = c0 + 16;     // mask col (0..63)
        const float b0 = mbase[mrow * 128 + c0];
        const float b1 = mbase[mrow * 128 + c1];
        P[row * 40 + ln] = __float2bfloat16(__expf(s0[r] + b0));
        P[row * 40 + 16 + ln] = __float2bfloat16(__expf(s1[r] + b1));
      }
    }
    __syncthreads();
#pragma unroll
    for (int i = 0; i < 2; i++) {
      bf16x8 pf = *(const bf16x8*)(&P[(w * 32 + i * 16 + ln) * 40 + quad * 8]);
      accO[i][0] = mfma16(pf, vf[0], accO[i][0]);
      accO[i][1] = mfma16(pf, vf[1], accO[i][1]);
    }
    __syncthreads();
  }
#pragma unroll
  for (int i = 0; i < 2; i++) {
#pragma unroll
    for (int r = 0; r < 4; r++) {
      const float rs = __shfl(accO[i][1][r], (lane & 48) + 4, 64);
      const float inv = 1.f / rs;
      const int row = w * 32 + i * 16 + quad * 4 + r;
      const int orow_i = (w < 2) ? 64 + row : row - 64;   // x2 -> 64.., x1 -> 0..
      const int token = tokbase + wiL * NTOK + orow_i;
      bf16* orow = xout + (size_t)token * 256 + hh * HDIM;
      orow[ln] = __float2bfloat16(accO[i][0][r] * inv);
      if (ln < 4) orow[16 + ln] = __float2bfloat16(accO[i][1][r] * inv);
    }
  }
}

// LN2 -> bf16 A-matrix [131072][128]. float4 loads + bf16x8 stores.
__global__ __launch_bounds__(256) void k_ln2(
    const float* __restrict__ out, const float* __restrict__ g2,
    const float* __restrict__ b2, bf16* __restrict__ A2) {
  const int row = blockIdx.x * 256 + threadIdx.x;
  const float4* xr4 = (const float4*)(out + (size_t)row * CC);
  float xv[CC];
#pragma unroll
  for (int k = 0; k < 30; k++) {
    const float4 v = xr4[k];
    xv[k * 4] = v.x; xv[k * 4 + 1] = v.y; xv[k * 4 + 2] = v.z; xv[k * 4 + 3] = v.w;
  }
  ln120(xv, g2, b2);
  bf16x8* dst8 = (bf16x8*)(A2 + (size_t)row * 128);
#pragma unroll
  for (int k = 0; k < 15; k++) {
    bf16x8 v;
#pragma unroll
    for (int j = 0; j < 8; j++) v[j] = f2bf_s(xv[k * 8 + j]);
    dst8[k] = v;
  }
  bf16x8 tail = {0, 0, 0, 0, 0, 0, 0, 0};
  dst8[15] = tail;
}

// FFN1 MFMA: h = gelu(A2@W11^T) * (A2@W12^T). grid (4, 512): 2048 blocks.
__global__ __launch_bounds__(256) void k_ffn1_mfma(
    const bf16* __restrict__ A2, const bf16* __restrict__ Bffn,
    const float* __restrict__ b11, const float* __restrict__ b12,
    bf16* __restrict__ h) {
  const int j = blockIdx.x * 4 + (threadIdx.x >> 6);  // pair index 0..15
  const int lane = threadIdx.x & 63;
  const int ln = lane & 15, quad = lane >> 4;
  bf16x8 b1f[4], b2f[4];
#pragma unroll
  for (int s = 0; s < 4; s++) {
    b1f[s] = *(const bf16x8*)(Bffn + (size_t)(j * 16 + ln) * 128 + s * 32 + quad * 8);
    b2f[s] = *(const bf16x8*)(Bffn + (size_t)(j * 16 + 256 + ln) * 128 + s * 32 + quad * 8);
  }
  const int col = j * 16 + ln;
  const float bias1 = (col < HID2) ? b11[col] : 0.f;
  const float bias2 = (col < HID2) ? b12[col] : 0.f;
  const int m_base = blockIdx.y * 256;
  for (int it = 0; it < 8; it++) {
    const int m0 = m_base + it * 32;
    f32x4 acc[2][2] = {};
    bf16x8 af[2][4];
#pragma unroll
    for (int mi = 0; mi < 2; mi++)
#pragma unroll
      for (int s = 0; s < 4; s++)
        af[mi][s] = *(const bf16x8*)(A2 + (size_t)(m0 + mi * 16 + ln) * 128 + s * 32 + quad * 8);
#pragma unroll
    for (int s = 0; s < 4; s++)
#pragma unroll
      for (int mi = 0; mi < 2; mi++) {
        acc[mi][0] = mfma16(af[mi][s], b1f[s], acc[mi][0]);
        acc[mi][1] = mfma16(af[mi][s], b2f[s], acc[mi][1]);
      }
    if (col < HID2) {
#pragma unroll
      for (int mi = 0; mi < 2; mi++)
#pragma unroll
        for (int r = 0; r < 4; r++) {
          const int row = m0 + mi * 16 + quad * 4 + r;
          const float a = acc[mi][0][r] + bias1;
          const float c = acc[mi][1][r] + bias2;
          const float ge = 0.5f * a * (1.f + erff(a * 0.70710678118654752f));
          h[(size_t)row * 256 + col] = __float2bfloat16(ge * c);
        }
    }
  }
}

// Output GEMMs, K=256 (padded), N=120. grid (1, 1024): 1024 blocks.
template <bool PROJ>
__global__ __launch_bounds__(256) void k_out_mfma(
    const bf16* __restrict__ A, const bf16* __restrict__ Bw,
    const float* __restrict__ bias, const float* __restrict__ xin,
    float* __restrict__ out) {
  const int w = threadIdx.x >> 6;
  const int lane = threadIdx.x & 63;
  const int ln = lane & 15, quad = lane >> 4;
  bf16x8 bfr[2][8];
#pragma unroll
  for (int nt = 0; nt < 2; nt++)
#pragma unroll
    for (int s = 0; s < 8; s++)
      bfr[nt][s] = *(const bf16x8*)(Bw + (size_t)((w * 2 + nt) * 16 + ln) * 256 + s * 32 + quad * 8);
  const int m_base = blockIdx.y * 128;
  for (int it = 0; it < 4; it++) {
    const int m0 = m_base + it * 32;
    f32x4 acc[2][2] = {};
    bf16x8 af[2][8];
#pragma unroll
    for (int mi = 0; mi < 2; mi++)
#pragma unroll
      for (int s = 0; s < 8; s++)
        af[mi][s] = *(const bf16x8*)(A + (size_t)(m0 + mi * 16 + ln) * 256 + s * 32 + quad * 8);
#pragma unroll
    for (int s = 0; s < 8; s++)
#pragma unroll
      for (int mi = 0; mi < 2; mi++)
#pragma unroll
        for (int nt = 0; nt < 2; nt++)
          acc[mi][nt] = mfma16(af[mi][s], bfr[nt][s], acc[mi][nt]);
#pragma unroll
    for (int mi = 0; mi < 2; mi++)
#pragma unroll
      for (int nt = 0; nt < 2; nt++) {
        const int colc = (w * 2 + nt) * 16 + ln;
        if (colc < CC) {
#pragma unroll
          for (int r = 0; r < 4; r++) {
            const int row = m0 + mi * 16 + quad * 4 + r;
            if (PROJ) {
              const size_t dst = token_src_offset(row);
              out[dst + colc] = xin[dst + colc] + bias[colc] + acc[mi][nt][r];
            } else {
              out[(size_t)row * CC + colc] += bias[colc] + acc[mi][nt][r];
            }
          }
        }
      }
  }
}

// ===========================================================================
// FALLBACK PATH (round-2 proven kernels; used only if ws is too small)
// ===========================================================================
__global__ __launch_bounds__(128) void k_attn_self_fb(
    const float* __restrict__ x, const float* __restrict__ g1,
    const float* __restrict__ b1, const float* __restrict__ wqkv,
    const float* __restrict__ bqkv, const float* __restrict__ mask,
    const float* __restrict__ rpb, const int* __restrict__ rpi,
    bf16* __restrict__ xout) {
  __shared__ float kl[NTOK][HDIM];
  __shared__ float vl[NTOK][HDIM];
  const int wi = blockIdx.x, hh = blockIdx.y, t = threadIdx.x;
  const int token = wi * NTOK + t;
  const float* xr = x + token_src_offset(token);
  float xv[CC];
#pragma unroll
  for (int k = 0; k < CC; k++) xv[k] = xr[k];
  ln120(xv, g1, b1);
  float q[HDIM];
  for (int j = 0; j < HDIM; j++) {
    const int c = hh * HDIM + j;
    q[j] = (dot120(xv, wqkv + (size_t)c * CC) + bqkv[c]) * SCALE_F;
    kl[t][j] = dot120(xv, wqkv + (size_t)(CC + c) * CC) + bqkv[CC + c];
    vl[t][j] = dot120(xv, wqkv + (size_t)(2 * CC + c) * CC) + bqkv[2 * CC + c];
  }
  __syncthreads();
  const float* mrow = mask + ((size_t)(wi & 255) * NTOK + t) * NTOK;
  const int* rrow = rpi + t * NTOK;
  float sum = 0.f;
  float o[HDIM];
#pragma unroll
  for (int i = 0; i < HDIM; i++) o[i] = 0.f;
  for (int m = 0; m < NTOK; m++) {
    float a0 = 0.f, a1 = 0.f, a2 = 0.f, a3 = 0.f;
#pragma unroll
    for (int i = 0; i < HDIM; i += 4) {
      a0 = fmaf(q[i], kl[m][i], a0);
      a1 = fmaf(q[i + 1], kl[m][i + 1], a1);
      a2 = fmaf(q[i + 2], kl[m][i + 2], a2);
      a3 = fmaf(q[i + 3], kl[m][i + 3], a3);
    }
    const float sc = (a0 + a1) + (a2 + a3) + rpb[rrow[m] * NHEADS + hh] + mrow[m];
    const float p = __expf(sc);
    sum += p;
#pragma unroll
    for (int i = 0; i < HDIM; i++) o[i] = fmaf(p, vl[m][i], o[i]);
  }
  const float inv = 1.f / sum;
  bf16* orow = xout + (size_t)token * HID2 + CC + hh * HDIM;
#pragma unroll
  for (int i = 0; i < HDIM; i++) orow[i] = __float2bfloat16(o[i] * inv);
}

__global__ __launch_bounds__(64) void k_attn_mut_fb(
    const float* __restrict__ x, const float* __restrict__ g1,
    const float* __restrict__ b1, const float* __restrict__ wqkv,
    const float* __restrict__ bqkv, const float* __restrict__ pos,
    const float* __restrict__ mask, bf16* __restrict__ xout) {
  __shared__ float kl[64][HDIM];
  __shared__ float vl[64][HDIM];
  const int wi = blockIdx.x, hh = blockIdx.y, which = blockIdx.z;
  const int t = threadIdx.x;
  const int qtok = which ? t : 64 + t;
  const int ktok = which ? 64 + t : t;
  const float* pr = pos + (size_t)t * CC;
  float xv[CC];
  {
    const float* xr = x + token_src_offset(wi * NTOK + ktok);
#pragma unroll
    for (int k = 0; k < CC; k++) xv[k] = xr[k];
    ln120(xv, g1, b1);
#pragma unroll
    for (int k = 0; k < CC; k++) xv[k] += pr[k];
    for (int j = 0; j < HDIM; j++) {
      const int c = hh * HDIM + j;
      kl[t][j] = dot120(xv, wqkv + (size_t)(CC + c) * CC) + bqkv[CC + c];
      vl[t][j] = dot120(xv, wqkv + (size_t)(2 * CC + c) * CC) + bqkv[2 * CC + c];
    }
  }
  float q[HDIM];
  {
    const float* xr = x + token_src_offset(wi * NTOK + qtok);
#pragma unroll
    for (int k = 0; k < CC; k++) xv[k] = xr[k];
    ln120(xv, g1, b1);
#pragma unroll
    for (int k = 0; k < CC; k++) xv[k] += pr[k];
    for (int j = 0; j < HDIM; j++) {
      const int c = hh * HDIM + j;
      q[j] = (dot120(xv, wqkv + (size_t)c * CC) + bqkv[c]) * SCALE_F;
    }
  }
  __syncthreads();
  const float* mrow = mask + ((size_t)(wi & 255) * NTOK + t) * NTOK;
  float sum = 0.f;
  float o[HDIM];
#pragma unroll
  for (int i = 0; i < HDIM; i++) o[i] = 0.f;
  for (int m = 0; m < 64; m++) {
    float a0 = 0.f, a1 = 0.f, a2 = 0.f, a3 = 0.f;
#pragma unroll
    for (int i = 0; i < HDIM; i += 4) {
      a0 = fmaf(q[i], kl[m][i], a0);
      a1 = fmaf(q[i + 1], kl[m][i + 1], a1);
      a2 = fmaf(q[i + 2], kl[m][i + 2], a2);
      a3 = fmaf(q[i + 3], kl[m][i + 3], a3);
    }
    const float p = __expf((a0 + a1) + (a2 + a3) + mrow[m]);
    sum += p;
#pragma unroll
    for (int i = 0; i < HDIM; i++) o[i] = fmaf(p, vl[m][i], o[i]);
  }
  const float inv = 1.f / sum;
  const int orow_i = which ? 64 + t : t;
  bf16* orow = xout + (size_t)(wi * NTOK + orow_i) * HID2 + hh * HDIM;
#pragma unroll
  for (int i = 0; i < HDIM; i++) orow[i] = __float2bfloat16(o[i] * inv);
}

template <int HALF>
__global__ __launch_bounds__(256) void k_proj_fb(
    const bf16* __restrict__ xout, const float* __restrict__ pw,
    const float* __restrict__ pb, const float* __restrict__ xin,
    float* __restrict__ out) {
  const int token = blockIdx.x * 256 + threadIdx.x;
  float xv[CC];
  const bf16* xr = xout + (size_t)token * HID2 + HALF * CC;
#pragma unroll
  for (int k = 0; k < CC; k++) xv[k] = __bfloat162float(xr[k]);
  const size_t dst = token_src_offset(token);
  for (int o = 0; o < CC; o++) {
    const float acc = dot120(xv, pw + (size_t)o * HID2 + HALF * CC);
    if (HALF == 0)
      out[dst + o] = xin[dst + o] + pb[o] + acc;
    else
      out[dst + o] += acc;
  }
}

__global__ __launch_bounds__(256) void k_ffn1_fb(
    const float* __restrict__ xres, const float* __restrict__ g,
    const float* __restrict__ bb, const float* __restrict__ w11,
    const float* __restrict__ b11, const float* __restrict__ w12,
    const float* __restrict__ b12, bf16* __restrict__ hbuf) {
  const int row = blockIdx.x * 256 + threadIdx.x;
  const float* xr = xres + (size_t)row * CC;
  float xv[CC];
#pragma unroll
  for (int k = 0; k < CC; k++) xv[k] = xr[k];
  ln120(xv, g, bb);
  bf16* hr = hbuf + (size_t)row * HID2;
  for (int o = 0; o < HID2; o++) {
    const float a = b11[o] + dot120(xv, w11 + (size_t)o * CC);
    const float c = b12[o] + dot120(xv, w12 + (size_t)o * CC);
    const float ge = 0.5f * a * (1.f + erff(a * 0.70710678118654752f));
    hr[o] = __float2bfloat16(ge * c);
  }
}

template <int HALF>
__global__ __launch_bounds__(256) void k_ffn2_fb(
    const bf16* __restrict__ hbuf, const float* __restrict__ w2,
    const float* __restrict__ b2f, float* __restrict__ out) {
  const int row = blockIdx.x * 256 + threadIdx.x;
  float xv[CC];
  const bf16* xr = hbuf + (size_t)row * HID2 + HALF * CC;
#pragma unroll
  for (int k = 0; k < CC; k++) xv[k] = __bfloat162float(xr[k]);
  float* orow = out + (size_t)row * CC;
  for (int o = 0; o < CC; o++) {
    float acc = dot120(xv, w2 + (size_t)o * HID2 + HALF * CC);
    if (HALF == 0) acc += b2f[o];
    orow[o] += acc;
  }
}

// ---------------------------------------------------------------------------
extern "C" void kernel_launch(void* const* d_in, const int* in_sizes, int n_in,
                              void* d_out, int out_size, void* d_ws, size_t ws_size,
                              hipStream_t stream) {
  const float* x          = (const float*)d_in[0];
  const float* attn_mask  = (const float*)d_in[1];
  const float* g1         = (const float*)d_in[2];
  const float* b1         = (const float*)d_in[3];
  const float* qkv_self_w = (const float*)d_in[4];
  const float* qkv_self_b = (const float*)d_in[5];
  const float* qkv_mut_w  = (const float*)d_in[6];
  const float* qkv_mut_b  = (const float*)d_in[7];
  const float* proj_w     = (const float*)d_in[8];
  const float* proj_b     = (const float*)d_in[9];
  const float* rpb_table  = (const float*)d_in[10];
  const float* pos_bias   = (const float*)d_in[11];
  const float* g2         = (const float*)d_in[12];
  const float* b2         = (const float*)d_in[13];
  const float* fc11_w     = (const float*)d_in[14];
  const float* fc11_b     = (const float*)d_in[15];
  const float* fc12_w     = (const float*)d_in[16];
  const float* fc12_b     = (const float*)d_in[17];
  const float* fc2_w      = (const float*)d_in[18];
  const float* fc2_b      = (const float*)d_in[19];
  const int*   rpi        = (const int*)d_in[20];
  float* out = (float*)d_out;

  // ws layout (bytes), gate unchanged:
  //   xout  @ 0           : 131072*256*2 = 67,108,864
  //   A1/A2 @ 67,108,864  : 131072*128*2 = 33,554,432
  //   Bffn  @ 100,663,296 : 131,072 ; Bfc2 +65,536 ; Bproj +65,536
  // d_out doubles as scratch until proj overwrites every element:
  //   qkA @ 0 (25,165,824) ; vt @ 25,165,824 (12,582,912)
  //   Wself2 @ 40,000,000 ; Wmut2 @ 40,200,000 ; posq2 @ 40,400,000
  //   biasC @ 41,000,000 (393,216) -> ends 41.4 MB < 62.9 MB
  const bool fast = ws_size >= (size_t)100925440;

  if (fast) {
    bf16* xout  = (bf16*)d_ws;
    bf16* hbuf  = xout;
    bf16* A1    = (bf16*)((char*)d_ws + 67108864);
    bf16* A2    = A1;
    bf16* Bffn  = (bf16*)((char*)d_ws + 100663296);
    bf16* Bfc2  = Bffn + 65536;
    bf16* Bproj = Bfc2 + 32768;

    bf16*  qkA    = (bf16*)d_out;
    bf16*  vtb    = (bf16*)((char*)d_out + 25165824);
    bf16*  Wself2 = (bf16*)((char*)d_out + 40000000);
    bf16*  Wmut2  = (bf16*)((char*)d_out + 40200000);
    float* posq2  = (float*)((char*)d_out + 40400000);
    float* biasC  = (float*)((char*)d_out + 41000000);

    k_prep<<<1088, 256, 0, stream>>>(fc11_w, fc12_w, fc2_w, proj_w,
                                     qkv_self_w, qkv_self_b, qkv_mut_w, qkv_mut_b,
                                     Bffn, Bfc2, Bproj, Wself2, Wmut2);
    k_posq2<<<144, 256, 0, stream>>>(pos_bias, qkv_mut_w, posq2);
    k_biasc<<<384, 256, 0, stream>>>(rpi, rpb_table, biasC);
    k_a1<<<512, 256, 0, stream>>>(x, g1, b1, A1);
    for (int c = 0; c < 4; c++) {
      k_qkv2<false><<<dim3(18, 512), 64, 0, stream>>>(A1, Wself2, nullptr, qkA, vtb, c * 32768);
      k_attn_self4<<<dim3(256, NHEADS), 256, 0, stream>>>(qkA, vtb, attn_mask, biasC, xout, c * 32768);
    }
    for (int c = 0; c < 4; c++) {
      k_qkv2<true><<<dim3(18, 512), 64, 0, stream>>>(A1, Wmut2, posq2, qkA, vtb, c * 32768);
      k_attn_mut4<<<dim3(256, NHEADS), 256, 0, stream>>>(qkA, vtb, attn_mask, xout, c * 32768);
    }
    k_out_mfma<true><<<dim3(1, 1024), 256, 0, stream>>>(xout, Bproj, proj_b, x, out);
    k_ln2<<<512, 256, 0, stream>>>(out, g2, b2, A2);
    k_ffn1_mfma<<<dim3(4, 512), 256, 0, stream>>>(A2, Bffn, fc11_b, fc12_b, hbuf);
    k_out_mfma<false><<<dim3(1, 1024), 256, 0, stream>>>(hbuf, Bfc2, fc2_b, nullptr, out);
  } else {
    bf16* xout = (bf16*)d_ws;
    bf16* hbuf = (bf16*)d_ws;
    k_attn_self_fb<<<dim3(1024, NHEADS), 128, 0, stream>>>(
        x, g1, b1, qkv_self_w, qkv_self_b, attn_mask, rpb_table, rpi, xout);
    k_attn_mut_fb<<<dim3(1024, NHEADS, 2), 64, 0, stream>>>(
        x, g1, b1, qkv_mut_w, qkv_mut_b, pos_bias, attn_mask, xout);
    k_proj_fb<0><<<512, 256, 0, stream>>>(xout, proj_w, proj_b, x, out);
    k_proj_fb<1><<<512, 256, 0, stream>>>(xout, proj_w, proj_b, x, out);
    k_ffn1_fb<<<512, 256, 0, stream>>>(out, g2, b2, fc11_w, fc11_b, fc12_w, fc12_b, hbuf);
    k_ffn2_fb<0><<<512, 256, 0, stream>>>(hbuf, fc2_w, fc2_b, out);
    k_ffn2_fb<1><<<512, 256, 0, stream>>>(hbuf, fc2_w, fc2_b, out);
  }
}

// Round 8
// 804.727 us; speedup vs baseline: 1.1051x; 1.1051x over previous
//
#include <hip/hip_runtime.h>
#include <hip/hip_bf16.h>
#include <math.h>

#define CC 120       // channels
#define NHEADS 6
#define HDIM 20      // head dim
#define NTOK 128     // tokens per window
#define HID2 240
#define SCALE_F 0.2236067977499790f  // 20^-0.5

typedef __hip_bfloat16 bf16;
typedef __attribute__((ext_vector_type(8))) short bf16x8;   // 8 bf16 (4 VGPRs)
typedef __attribute__((ext_vector_type(4))) float f32x4;    // MFMA accumulator

__device__ inline f32x4 mfma16(bf16x8 a, bf16x8 b, f32x4 c) {
  return __builtin_amdgcn_mfma_f32_16x16x32_bf16(a, b, c, 0, 0, 0);
}

__device__ inline short f2bf_s(float f) {
  bf16 h = __float2bfloat16(f);
  return *reinterpret_cast<short*>(&h);
}

// ---------------------------------------------------------------------------
// token -> rolled spatial source position (also the scatter destination for
// window-reverse + un-roll, which is the same map).
__device__ inline size_t token_src_offset(int token) {
  const int wi = token >> 7, n = token & 127;
  const int b_ = wi >> 8, rem = wi & 255;
  const int dB = rem >> 6, hB = (rem >> 3) & 7, wB = rem & 7;
  const int dI = n >> 6, hI = (n >> 3) & 7, wI = n & 7;
  const int d = dB * 2 + dI, h = hB * 8 + hI, w = wB * 8 + wI;
  const int ds = (d + 1) & 7, hs = (h + 4) & 63, ws2 = (w + 4) & 63;
  return (((size_t)(b_ * 8 + ds) * 64 + hs) * 64 + ws2) * CC;
}

__device__ inline void ln120(float* xv, const float* __restrict__ g,
                             const float* __restrict__ bb) {
  float s0 = 0.f, s1 = 0.f, s2 = 0.f, s3 = 0.f;
#pragma unroll
  for (int k = 0; k < CC; k += 4) {
    s0 += xv[k]; s1 += xv[k + 1]; s2 += xv[k + 2]; s3 += xv[k + 3];
  }
  const float mean = ((s0 + s1) + (s2 + s3)) * (1.f / 120.f);
  float v0 = 0.f, v1 = 0.f, v2 = 0.f, v3 = 0.f;
#pragma unroll
  for (int k = 0; k < CC; k += 4) {
    float d0 = xv[k] - mean, d1 = xv[k + 1] - mean;
    float d2 = xv[k + 2] - mean, d3 = xv[k + 3] - mean;
    v0 += d0 * d0; v1 += d1 * d1; v2 += d2 * d2; v3 += d3 * d3;
  }
  const float rstd = rsqrtf(((v0 + v1) + (v2 + v3)) * (1.f / 120.f) + 1e-5f);
#pragma unroll
  for (int k = 0; k < CC; k++) xv[k] = (xv[k] - mean) * rstd * g[k] + bb[k];
}

__device__ inline float dot120(const float* xv, const float* __restrict__ wr) {
  float a0 = 0.f, a1 = 0.f, a2 = 0.f, a3 = 0.f;
#pragma unroll
  for (int k = 0; k < CC; k += 4) {
    a0 = fmaf(xv[k], wr[k], a0);
    a1 = fmaf(xv[k + 1], wr[k + 1], a1);
    a2 = fmaf(xv[k + 2], wr[k + 2], a2);
    a3 = fmaf(xv[k + 3], wr[k + 3], a3);
  }
  return (a0 + a1) + (a2 + a3);
}

// ===========================================================================
// FAST PATH
// ===========================================================================
// Weight prep.
//  Bffn [512][128]: rows 0..239 = W11, 256..495 = W12 (K pad, bias separate)
//  Bfc2 [128][256], Bproj [128][256]
//  Wself2/Wmut2 [576][128]: rows 0..191 q (heads padded to 32, SCALE folded),
//    192..383 k, 384..575 v. col 120 = bias (A1 col120 == 1), pads 0.
//    v-row pad chan 20 = e120 (=> V col 20 == 1.0: PV computes softmax rowsum).
__global__ __launch_bounds__(256) void k_prep(
    const float* __restrict__ w11, const float* __restrict__ w12,
    const float* __restrict__ fc2w, const float* __restrict__ projw,
    const float* __restrict__ wself, const float* __restrict__ bself,
    const float* __restrict__ wmut, const float* __restrict__ bmut,
    bf16* __restrict__ Bffn, bf16* __restrict__ Bfc2, bf16* __restrict__ Bproj,
    bf16* __restrict__ Wself2, bf16* __restrict__ Wmut2) {
  const int i = blockIdx.x * 256 + threadIdx.x;
  if (i < 65536) {
    const int r = i >> 7, k = i & 127;
    float v = 0.f;
    if (k < 120) {
      if (r < 240) v = w11[r * 120 + k];
      else if (r >= 256 && r < 496) v = w12[(r - 256) * 120 + k];
    }
    Bffn[i] = __float2bfloat16(v);
  } else if (i < 98304) {
    const int j = i - 65536, r = j >> 8, k = j & 255;
    Bfc2[j] = __float2bfloat16((r < 120 && k < 240) ? fc2w[r * 240 + k] : 0.f);
  } else if (i < 131072) {
    const int j = i - 98304, r = j >> 8, k = j & 255;
    Bproj[j] = __float2bfloat16((r < 120 && k < 240) ? projw[r * 240 + k] : 0.f);
  } else if (i < 278528) {
    const int j = (i - 131072) % 73728;
    const bool is_self = (i - 131072) < 73728;
    const float* w = is_self ? wself : wmut;
    const float* b = is_self ? bself : bmut;
    const int r = j >> 7, k = j & 127;
    const int grp = r / 192;              // 0=q 1=k 2=v
    const int rr = r % 192;
    const int hh = rr >> 5, jj = rr & 31;
    float v = 0.f;
    if (jj < 20) {
      const int orow = grp * 120 + hh * 20 + jj;
      if (k < 120) v = w[orow * 120 + k];
      else if (k == 120) v = b[orow];
      if (grp == 0) v *= SCALE_F;
    } else if (grp == 2 && jj == 20 && k == 120) {
      v = 1.0f;                           // rowsum column
    }
    (is_self ? Wself2 : Wmut2)[j] = __float2bfloat16(v);
  }
}

// posq2[t63][c] = dot(pos[t63], W'_c over real channels); SCALE on q cols.
__global__ __launch_bounds__(256) void k_posq2(
    const float* __restrict__ pos, const float* __restrict__ wmut,
    float* __restrict__ posq) {
  const int i = blockIdx.x * 256 + threadIdx.x;
  if (i >= 64 * 576) return;
  const int t63 = i / 576, c = i % 576;
  const int grp = c / 192, rr = c % 192;
  const int hh = rr >> 5, jj = rr & 31;
  float v = 0.f;
  if (jj < 20) {
    v = dot120(pos + (size_t)t63 * CC, wmut + (size_t)(grp * 120 + hh * 20 + jj) * CC);
    if (grp == 0) v *= SCALE_F;
  }
  posq[i] = v;
}

// biasC[h][row][col] = rpb[rpi[row,col]*6+h]  (de-gathered rel-pos bias, fp32)
__global__ __launch_bounds__(256) void k_biasc(
    const int* __restrict__ rpi, const float* __restrict__ rpb,
    float* __restrict__ biasC) {
  const int i = blockIdx.x * 256 + threadIdx.x;
  if (i >= NHEADS * 16384) return;
  const int h = i >> 14, rc = i & 16383;
  biasC[i] = rpb[rpi[rc] * NHEADS + h];
}

// LN1 + roll + partition -> A1 bf16 [131072][128], col 120 = 1.0 (bias col).
__global__ __launch_bounds__(256) void k_a1(
    const float* __restrict__ x, const float* __restrict__ g1,
    const float* __restrict__ b1, bf16* __restrict__ A1) {
  const int token = blockIdx.x * 256 + threadIdx.x;
  const float4* xr4 = (const float4*)(x + token_src_offset(token));
  float xv[CC];
#pragma unroll
  for (int k = 0; k < 30; k++) {
    const float4 v = xr4[k];
    xv[k * 4] = v.x; xv[k * 4 + 1] = v.y; xv[k * 4 + 2] = v.z; xv[k * 4 + 3] = v.w;
  }
  ln120(xv, g1, b1);
  bf16x8* dst8 = (bf16x8*)(A1 + (size_t)token * 128);
#pragma unroll
  for (int k = 0; k < 15; k++) {
    bf16x8 v;
#pragma unroll
    for (int j = 0; j < 8; j++) v[j] = f2bf_s(xv[k * 8 + j]);
    dst8[k] = v;
  }
  bf16x8 tail = {0, 0, 0, 0, 0, 0, 0, 0};
  tail[0] = f2bf_s(1.0f);
  dst8[15] = tail;
}

// ---------------------------------------------------------------------------
// FUSED QKV + attention. Block = window (1024 blocks), 4 waves; loop 6 heads.
// Wave w owns rows [w*32, w*32+32): computes q/k/v via MFMA (A-frags in regs,
// loaded once), stages k -> kS, v^T -> vS (cross-wave), q -> its private qP
// slice; after barrier runs the attention core. qP is reused for P (wave-
// private slices: LDS ops within a wave are in-order, no barrier needed).
// LDS strides: 40 (rows, 80 B) and 136 (vchan rows, 272 B) are conflict-free
// and keep b128 reads 16B-aligned.
template <bool MUT>
__global__ __launch_bounds__(256, 4) void k_fattn(
    const bf16* __restrict__ A1, const bf16* __restrict__ W2,
    const float* __restrict__ posq, const float* __restrict__ mask,
    const float* __restrict__ biasC, bf16* __restrict__ xout) {
  __shared__ bf16 kS[128 * 40];
  __shared__ bf16 vS[32 * 136];
  __shared__ bf16 qP[128 * 40];   // q staging, then P
  const int wi = blockIdx.x;
  const int w = threadIdx.x >> 6, lane = threadIdx.x & 63;
  const int ln = lane & 15, quad = lane >> 4;
  // A-fragments for this wave's 32 rows (reused across 6 heads x 3 groups)
  bf16x8 af[2][4];
#pragma unroll
  for (int mi = 0; mi < 2; mi++)
#pragma unroll
    for (int s = 0; s < 4; s++)
      af[mi][s] = *(const bf16x8*)(A1 + (size_t)(wi * NTOK + w * 32 + mi * 16 + ln) * 128 + s * 32 + quad * 8);
  const float* mbase = mask + (size_t)(wi & 255) * 16384;

  for (int hh = 0; hh < NHEADS; hh++) {
    // ---- QKV phase: group g = 0(q) 1(k) 2(v) ----
#pragma unroll
    for (int g = 0; g < 3; g++) {
      bf16x8 bfr[2][4];
#pragma unroll
      for (int nt = 0; nt < 2; nt++)
#pragma unroll
        for (int s = 0; s < 4; s++)
          bfr[nt][s] = *(const bf16x8*)(W2 + (size_t)(g * 192 + hh * 32 + nt * 16 + ln) * 128 + s * 32 + quad * 8);
      f32x4 acc[2][2] = {};
#pragma unroll
      for (int s = 0; s < 4; s++)
#pragma unroll
        for (int mi = 0; mi < 2; mi++)
#pragma unroll
          for (int nt = 0; nt < 2; nt++)
            acc[mi][nt] = mfma16(af[mi][s], bfr[nt][s], acc[mi][nt]);
#pragma unroll
      for (int mi = 0; mi < 2; mi++)
#pragma unroll
        for (int nt = 0; nt < 2; nt++)
#pragma unroll
          for (int r = 0; r < 4; r++) {
            const int lrow = w * 32 + mi * 16 + quad * 4 + r;
            float v = acc[mi][nt][r];
            if (MUT) v += posq[(lrow & 63) * 576 + g * 192 + hh * 32 + nt * 16 + ln];
            const short bv = f2bf_s(v);
            if (g == 0)      *(short*)&qP[lrow * 40 + nt * 16 + ln] = bv;
            else if (g == 1) *(short*)&kS[lrow * 40 + nt * 16 + ln] = bv;
            else             *(short*)&vS[(nt * 16 + ln) * 136 + lrow] = bv;
          }
    }
    __syncthreads();
    // ---- attention phase ----
    bf16x8 qf[2];
#pragma unroll
    for (int i = 0; i < 2; i++)
      qf[i] = *(const bf16x8*)(&qP[(w * 32 + i * 16 + ln) * 40 + quad * 8]);
    f32x4 accO[2][2];
#pragma unroll
    for (int i = 0; i < 2; i++)
#pragma unroll
      for (int nt = 0; nt < 2; nt++) accO[i][nt] = (f32x4){0.f, 0.f, 0.f, 0.f};
    const int kb = MUT ? ((w < 2) ? 64 : 0) : 0;
    const int nchunk = MUT ? 2 : 4;
    for (int chunk = 0; chunk < nchunk; chunk++) {
      const int key0 = kb + chunk * 32;
      bf16x8 kf[2], vf[2];
      kf[0] = *(const bf16x8*)(&kS[(key0 + ln) * 40 + quad * 8]);
      kf[1] = *(const bf16x8*)(&kS[(key0 + 16 + ln) * 40 + quad * 8]);
      vf[0] = *(const bf16x8*)(&vS[ln * 136 + key0 + quad * 8]);
      vf[1] = *(const bf16x8*)(&vS[(16 + ln) * 136 + key0 + quad * 8]);
#pragma unroll
      for (int i = 0; i < 2; i++) {
        f32x4 s0 = mfma16(qf[i], kf[0], (f32x4){0.f, 0.f, 0.f, 0.f});
        f32x4 s1 = mfma16(qf[i], kf[1], (f32x4){0.f, 0.f, 0.f, 0.f});
#pragma unroll
        for (int r = 0; r < 4; r++) {
          const int row = w * 32 + i * 16 + quad * 4 + r;
          float b0, b1;
          if (MUT) {
            const int mrow = row & 63;
            b0 = mbase[mrow * 128 + chunk * 32 + ln];
            b1 = mbase[mrow * 128 + chunk * 32 + 16 + ln];
          } else {
            const int c0 = chunk * 32 + ln;
            b0 = biasC[hh * 16384 + row * 128 + c0] + mbase[row * 128 + c0];
            b1 = biasC[hh * 16384 + row * 128 + c0 + 16] + mbase[row * 128 + c0 + 16];
          }
          *(short*)&qP[row * 40 + ln] = f2bf_s(__expf(s0[r] + b0));
          *(short*)&qP[row * 40 + 16 + ln] = f2bf_s(__expf(s1[r] + b1));
        }
      }
#pragma unroll
      for (int i = 0; i < 2; i++) {
        bf16x8 pf = *(const bf16x8*)(&qP[(w * 32 + i * 16 + ln) * 40 + quad * 8]);
        accO[i][0] = mfma16(pf, vf[0], accO[i][0]);
        accO[i][1] = mfma16(pf, vf[1], accO[i][1]);
      }
    }
    // ---- epilogue: rowsum (V pad col 20) + normalize + write ----
#pragma unroll
    for (int i = 0; i < 2; i++) {
#pragma unroll
      for (int r = 0; r < 4; r++) {
        const float rs = __shfl(accO[i][1][r], (lane & 48) + 4, 64);
        const float inv = 1.f / rs;
        const int row = w * 32 + i * 16 + quad * 4 + r;
        const int orow_i = MUT ? ((w < 2) ? 64 + row : row - 64) : row;
        const int token = wi * NTOK + orow_i;
        bf16* orow = xout + (size_t)token * 256 + (MUT ? 0 : CC) + hh * HDIM;
        orow[ln] = __float2bfloat16(accO[i][0][r] * inv);
        if (ln < 4) orow[16 + ln] = __float2bfloat16(accO[i][1][r] * inv);
      }
    }
    __syncthreads();   // protect kS/vS/qP before next head's QKV overwrite
  }
}

// LN2 -> bf16 A-matrix [131072][128]. float4 loads + bf16x8 stores.
__global__ __launch_bounds__(256) void k_ln2(
    const float* __restrict__ out, const float* __restrict__ g2,
    const float* __restrict__ b2, bf16* __restrict__ A2) {
  const int row = blockIdx.x * 256 + threadIdx.x;
  const float4* xr4 = (const float4*)(out + (size_t)row * CC);
  float xv[CC];
#pragma unroll
  for (int k = 0; k < 30; k++) {
    const float4 v = xr4[k];
    xv[k * 4] = v.x; xv[k * 4 + 1] = v.y; xv[k * 4 + 2] = v.z; xv[k * 4 + 3] = v.w;
  }
  ln120(xv, g2, b2);
  bf16x8* dst8 = (bf16x8*)(A2 + (size_t)row * 128);
#pragma unroll
  for (int k = 0; k < 15; k++) {
    bf16x8 v;
#pragma unroll
    for (int j = 0; j < 8; j++) v[j] = f2bf_s(xv[k * 8 + j]);
    dst8[k] = v;
  }
  bf16x8 tail = {0, 0, 0, 0, 0, 0, 0, 0};
  dst8[15] = tail;
}

// FFN1 MFMA: h = gelu(A2@W11^T) * (A2@W12^T). grid (4, 256) — R6 config.
__global__ __launch_bounds__(256) void k_ffn1_mfma(
    const bf16* __restrict__ A2, const bf16* __restrict__ Bffn,
    const float* __restrict__ b11, const float* __restrict__ b12,
    bf16* __restrict__ h) {
  const int j = blockIdx.x * 4 + (threadIdx.x >> 6);  // pair index 0..15
  const int lane = threadIdx.x & 63;
  const int ln = lane & 15, quad = lane >> 4;
  bf16x8 b1f[4], b2f[4];
#pragma unroll
  for (int s = 0; s < 4; s++) {
    b1f[s] = *(const bf16x8*)(Bffn + (size_t)(j * 16 + ln) * 128 + s * 32 + quad * 8);
    b2f[s] = *(const bf16x8*)(Bffn + (size_t)(j * 16 + 256 + ln) * 128 + s * 32 + quad * 8);
  }
  const int col = j * 16 + ln;
  const float bias1 = (col < HID2) ? b11[col] : 0.f;
  const float bias2 = (col < HID2) ? b12[col] : 0.f;
  const int m_base = blockIdx.y * 512;
  for (int it = 0; it < 16; it++) {
    const int m0 = m_base + it * 32;
    f32x4 acc[2][2] = {};
    bf16x8 af[2][4];
#pragma unroll
    for (int mi = 0; mi < 2; mi++)
#pragma unroll
      for (int s = 0; s < 4; s++)
        af[mi][s] = *(const bf16x8*)(A2 + (size_t)(m0 + mi * 16 + ln) * 128 + s * 32 + quad * 8);
#pragma unroll
    for (int s = 0; s < 4; s++)
#pragma unroll
      for (int mi = 0; mi < 2; mi++) {
        acc[mi][0] = mfma16(af[mi][s], b1f[s], acc[mi][0]);
        acc[mi][1] = mfma16(af[mi][s], b2f[s], acc[mi][1]);
      }
    if (col < HID2) {
#pragma unroll
      for (int mi = 0; mi < 2; mi++)
#pragma unroll
        for (int r = 0; r < 4; r++) {
          const int row = m0 + mi * 16 + quad * 4 + r;
          const float a = acc[mi][0][r] + bias1;
          const float c = acc[mi][1][r] + bias2;
          const float ge = 0.5f * a * (1.f + erff(a * 0.70710678118654752f));
          h[(size_t)row * 256 + col] = __float2bfloat16(ge * c);
        }
    }
  }
}

// Output GEMMs, K=256 (padded), N=120. grid (1, 1024).
template <bool PROJ>
__global__ __launch_bounds__(256) void k_out_mfma(
    const bf16* __restrict__ A, const bf16* __restrict__ Bw,
    const float* __restrict__ bias, const float* __restrict__ xin,
    float* __restrict__ out) {
  const int w = threadIdx.x >> 6;
  const int lane = threadIdx.x & 63;
  const int ln = lane & 15, quad = lane >> 4;
  bf16x8 bfr[2][8];
#pragma unroll
  for (int nt = 0; nt < 2; nt++)
#pragma unroll
    for (int s = 0; s < 8; s++)
      bfr[nt][s] = *(const bf16x8*)(Bw + (size_t)((w * 2 + nt) * 16 + ln) * 256 + s * 32 + quad * 8);
  const int m_base = blockIdx.y * 128;
  for (int it = 0; it < 4; it++) {
    const int m0 = m_base + it * 32;
    f32x4 acc[2][2] = {};
    bf16x8 af[2][8];
#pragma unroll
    for (int mi = 0; mi < 2; mi++)
#pragma unroll
      for (int s = 0; s < 8; s++)
        af[mi][s] = *(const bf16x8*)(A + (size_t)(m0 + mi * 16 + ln) * 256 + s * 32 + quad * 8);
#pragma unroll
    for (int s = 0; s < 8; s++)
#pragma unroll
      for (int mi = 0; mi < 2; mi++)
#pragma unroll
        for (int nt = 0; nt < 2; nt++)
          acc[mi][nt] = mfma16(af[mi][s], bfr[nt][s], acc[mi][nt]);
#pragma unroll
    for (int mi = 0; mi < 2; mi++)
#pragma unroll
      for (int nt = 0; nt < 2; nt++) {
        const int colc = (w * 2 + nt) * 16 + ln;
        if (colc < CC) {
#pragma unroll
          for (int r = 0; r < 4; r++) {
            const int row = m0 + mi * 16 + quad * 4 + r;
            if (PROJ) {
              const size_t dst = token_src_offset(row);
              out[dst + colc] = xin[dst + colc] + bias[colc] + acc[mi][nt][r];
            } else {
              out[(size_t)row * CC + colc] += bias[colc] + acc[mi][nt][r];
            }
          }
        }
      }
  }
}

// ===========================================================================
// FALLBACK PATH (round-2 proven kernels; used only if ws is too small)
// ===========================================================================
__global__ __launch_bounds__(128) void k_attn_self_fb(
    const float* __restrict__ x, const float* __restrict__ g1,
    const float* __restrict__ b1, const float* __restrict__ wqkv,
    const float* __restrict__ bqkv, const float* __restrict__ mask,
    const float* __restrict__ rpb, const int* __restrict__ rpi,
    bf16* __restrict__ xout) {
  __shared__ float kl[NTOK][HDIM];
  __shared__ float vl[NTOK][HDIM];
  const int wi = blockIdx.x, hh = blockIdx.y, t = threadIdx.x;
  const int token = wi * NTOK + t;
  const float* xr = x + token_src_offset(token);
  float xv[CC];
#pragma unroll
  for (int k = 0; k < CC; k++) xv[k] = xr[k];
  ln120(xv, g1, b1);
  float q[HDIM];
  for (int j = 0; j < HDIM; j++) {
    const int c = hh * HDIM + j;
    q[j] = (dot120(xv, wqkv + (size_t)c * CC) + bqkv[c]) * SCALE_F;
    kl[t][j] = dot120(xv, wqkv + (size_t)(CC + c) * CC) + bqkv[CC + c];
    vl[t][j] = dot120(xv, wqkv + (size_t)(2 * CC + c) * CC) + bqkv[2 * CC + c];
  }
  __syncthreads();
  const float* mrow = mask + ((size_t)(wi & 255) * NTOK + t) * NTOK;
  const int* rrow = rpi + t * NTOK;
  float sum = 0.f;
  float o[HDIM];
#pragma unroll
  for (int i = 0; i < HDIM; i++) o[i] = 0.f;
  for (int m = 0; m < NTOK; m++) {
    float a0 = 0.f, a1 = 0.f, a2 = 0.f, a3 = 0.f;
#pragma unroll
    for (int i = 0; i < HDIM; i += 4) {
      a0 = fmaf(q[i], kl[m][i], a0);
      a1 = fmaf(q[i + 1], kl[m][i + 1], a1);
      a2 = fmaf(q[i + 2], kl[m][i + 2], a2);
      a3 = fmaf(q[i + 3], kl[m][i + 3], a3);
    }
    const float sc = (a0 + a1) + (a2 + a3) + rpb[rrow[m] * NHEADS + hh] + mrow[m];
    const float p = __expf(sc);
    sum += p;
#pragma unroll
    for (int i = 0; i < HDIM; i++) o[i] = fmaf(p, vl[m][i], o[i]);
  }
  const float inv = 1.f / sum;
  bf16* orow = xout + (size_t)token * HID2 + CC + hh * HDIM;
#pragma unroll
  for (int i = 0; i < HDIM; i++) orow[i] = __float2bfloat16(o[i] * inv);
}

__global__ __launch_bounds__(64) void k_attn_mut_fb(
    const float* __restrict__ x, const float* __restrict__ g1,
    const float* __restrict__ b1, const float* __restrict__ wqkv,
    const float* __restrict__ bqkv, const float* __restrict__ pos,
    const float* __restrict__ mask, bf16* __restrict__ xout) {
  __shared__ float kl[64][HDIM];
  __shared__ float vl[64][HDIM];
  const int wi = blockIdx.x, hh = blockIdx.y, which = blockIdx.z;
  const int t = threadIdx.x;
  const int qtok = which ? t : 64 + t;
  const int ktok = which ? 64 + t : t;
  const float* pr = pos + (size_t)t * CC;
  float xv[CC];
  {
    const float* xr = x + token_src_offset(wi * NTOK + ktok);
#pragma unroll
    for (int k = 0; k < CC; k++) xv[k] = xr[k];
    ln120(xv, g1, b1);
#pragma unroll
    for (int k = 0; k < CC; k++) xv[k] += pr[k];
    for (int j = 0; j < HDIM; j++) {
      const int c = hh * HDIM + j;
      kl[t][j] = dot120(xv, wqkv + (size_t)(CC + c) * CC) + bqkv[CC + c];
      vl[t][j] = dot120(xv, wqkv + (size_t)(2 * CC + c) * CC) + bqkv[2 * CC + c];
    }
  }
  float q[HDIM];
  {
    const float* xr = x + token_src_offset(wi * NTOK + qtok);
#pragma unroll
    for (int k = 0; k < CC; k++) xv[k] = xr[k];
    ln120(xv, g1, b1);
#pragma unroll
    for (int k = 0; k < CC; k++) xv[k] += pr[k];
    for (int j = 0; j < HDIM; j++) {
      const int c = hh * HDIM + j;
      q[j] = (dot120(xv, wqkv + (size_t)c * CC) + bqkv[c]) * SCALE_F;
    }
  }
  __syncthreads();
  const float* mrow = mask + ((size_t)(wi & 255) * NTOK + t) * NTOK;
  float sum = 0.f;
  float o[HDIM];
#pragma unroll
  for (int i = 0; i < HDIM; i++) o[i] = 0.f;
  for (int m = 0; m < 64; m++) {
    float a0 = 0.f, a1 = 0.f, a2 = 0.f, a3 = 0.f;
#pragma unroll
    for (int i = 0; i < HDIM; i += 4) {
      a0 = fmaf(q[i], kl[m][i], a0);
      a1 = fmaf(q[i + 1], kl[m][i + 1], a1);
      a2 = fmaf(q[i + 2], kl[m][i + 2], a2);
      a3 = fmaf(q[i + 3], kl[m][i + 3], a3);
    }
    const float p = __expf((a0 + a1) + (a2 + a3) + mrow[m]);
    sum += p;
#pragma unroll
    for (int i = 0; i < HDIM; i++) o[i] = fmaf(p, vl[m][i], o[i]);
  }
  const float inv = 1.f / sum;
  const int orow_i = which ? 64 + t : t;
  bf16* orow = xout + (size_t)(wi * NTOK + orow_i) * HID2 + hh * HDIM;
#pragma unroll
  for (int i = 0; i < HDIM; i++) orow[i] = __float2bfloat16(o[i] * inv);
}

template <int HALF>
__global__ __launch_bounds__(256) void k_proj_fb(
    const bf16* __restrict__ xout, const float* __restrict__ pw,
    const float* __restrict__ pb, const float* __restrict__ xin,
    float* __restrict__ out) {
  const int token = blockIdx.x * 256 + threadIdx.x;
  float xv[CC];
  const bf16* xr = xout + (size_t)token * HID2 + HALF * CC;
#pragma unroll
  for (int k = 0; k < CC; k++) xv[k] = __bfloat162float(xr[k]);
  const size_t dst = token_src_offset(token);
  for (int o = 0; o < CC; o++) {
    const float acc = dot120(xv, pw + (size_t)o * HID2 + HALF * CC);
    if (HALF == 0)
      out[dst + o] = xin[dst + o] + pb[o] + acc;
    else
      out[dst + o] += acc;
  }
}

__global__ __launch_bounds__(256) void k_ffn1_fb(
    const float* __restrict__ xres, const float* __restrict__ g,
    const float* __restrict__ bb, const float* __restrict__ w11,
    const float* __restrict__ b11, const float* __restrict__ w12,
    const float* __restrict__ b12, bf16* __restrict__ hbuf) {
  const int row = blockIdx.x * 256 + threadIdx.x;
  const float* xr = xres + (size_t)row * CC;
  float xv[CC];
#pragma unroll
  for (int k = 0; k < CC; k++) xv[k] = xr[k];
  ln120(xv, g, bb);
  bf16* hr = hbuf + (size_t)row * HID2;
  for (int o = 0; o < HID2; o++) {
    const float a = b11[o] + dot120(xv, w11 + (size_t)o * CC);
    const float c = b12[o] + dot120(xv, w12 + (size_t)o * CC);
    const float ge = 0.5f * a * (1.f + erff(a * 0.70710678118654752f));
    hr[o] = __float2bfloat16(ge * c);
  }
}

template <int HALF>
__global__ __launch_bounds__(256) void k_ffn2_fb(
    const bf16* __restrict__ hbuf, const float* __restrict__ w2,
    const float* __restrict__ b2f, float* __restrict__ out) {
  const int row = blockIdx.x * 256 + threadIdx.x;
  float xv[CC];
  const bf16* xr = hbuf + (size_t)row * HID2 + HALF * CC;
#pragma unroll
  for (int k = 0; k < CC; k++) xv[k] = __bfloat162float(xr[k]);
  float* orow = out + (size_t)row * CC;
  for (int o = 0; o < CC; o++) {
    float acc = dot120(xv, w2 + (size_t)o * HID2 + HALF * CC);
    if (HALF == 0) acc += b2f[o];
    orow[o] += acc;
  }
}

// ---------------------------------------------------------------------------
extern "C" void kernel_launch(void* const* d_in, const int* in_sizes, int n_in,
                              void* d_out, int out_size, void* d_ws, size_t ws_size,
                              hipStream_t stream) {
  const float* x          = (const float*)d_in[0];
  const float* attn_mask  = (const float*)d_in[1];
  const float* g1         = (const float*)d_in[2];
  const float* b1         = (const float*)d_in[3];
  const float* qkv_self_w = (const float*)d_in[4];
  const float* qkv_self_b = (const float*)d_in[5];
  const float* qkv_mut_w  = (const float*)d_in[6];
  const float* qkv_mut_b  = (const float*)d_in[7];
  const float* proj_w     = (const float*)d_in[8];
  const float* proj_b     = (const float*)d_in[9];
  const float* rpb_table  = (const float*)d_in[10];
  const float* pos_bias   = (const float*)d_in[11];
  const float* g2         = (const float*)d_in[12];
  const float* b2         = (const float*)d_in[13];
  const float* fc11_w     = (const float*)d_in[14];
  const float* fc11_b     = (const float*)d_in[15];
  const float* fc12_w     = (const float*)d_in[16];
  const float* fc12_b     = (const float*)d_in[17];
  const float* fc2_w      = (const float*)d_in[18];
  const float* fc2_b      = (const float*)d_in[19];
  const int*   rpi        = (const int*)d_in[20];
  float* out = (float*)d_out;

  // ws layout (bytes), gate unchanged:
  //   xout  @ 0           : 131072*256*2 = 67,108,864
  //   A1/A2 @ 67,108,864  : 131072*128*2 = 33,554,432
  //   Bffn  @ 100,663,296 : 131,072 ; Bfc2 +65,536 ; Bproj +65,536
  // d_out doubles as scratch until proj overwrites every element:
  //   Wself2 @ 40,000,000 ; Wmut2 @ 40,200,000 ; posq2 @ 40,400,000
  //   biasC @ 41,000,000 (393,216) -> ends 41.4 MB < 62.9 MB
  const bool fast = ws_size >= (size_t)100925440;

  if (fast) {
    bf16* xout  = (bf16*)d_ws;
    bf16* hbuf  = xout;
    bf16* A1    = (bf16*)((char*)d_ws + 67108864);
    bf16* A2    = A1;
    bf16* Bffn  = (bf16*)((char*)d_ws + 100663296);
    bf16* Bfc2  = Bffn + 65536;
    bf16* Bproj = Bfc2 + 32768;

    bf16*  Wself2 = (bf16*)((char*)d_out + 40000000);
    bf16*  Wmut2  = (bf16*)((char*)d_out + 40200000);
    float* posq2  = (float*)((char*)d_out + 40400000);
    float* biasC  = (float*)((char*)d_out + 41000000);

    k_prep<<<1088, 256, 0, stream>>>(fc11_w, fc12_w, fc2_w, proj_w,
                                     qkv_self_w, qkv_self_b, qkv_mut_w, qkv_mut_b,
                                     Bffn, Bfc2, Bproj, Wself2, Wmut2);
    k_posq2<<<144, 256, 0, stream>>>(pos_bias, qkv_mut_w, posq2);
    k_biasc<<<384, 256, 0, stream>>>(rpi, rpb_table, biasC);
    k_a1<<<512, 256, 0, stream>>>(x, g1, b1, A1);
    k_fattn<false><<<1024, 256, 0, stream>>>(A1, Wself2, nullptr, attn_mask, biasC, xout);
    k_fattn<true><<<1024, 256, 0, stream>>>(A1, Wmut2, posq2, attn_mask, nullptr, xout);
    k_out_mfma<true><<<dim3(1, 1024), 256, 0, stream>>>(xout, Bproj, proj_b, x, out);
    k_ln2<<<512, 256, 0, stream>>>(out, g2, b2, A2);
    k_ffn1_mfma<<<dim3(4, 256), 256, 0, stream>>>(A2, Bffn, fc11_b, fc12_b, hbuf);
    k_out_mfma<false><<<dim3(1, 1024), 256, 0, stream>>>(hbuf, Bfc2, fc2_b, nullptr, out);
  } else {
    bf16* xout = (bf16*)d_ws;
    bf16* hbuf = (bf16*)d_ws;
    k_attn_self_fb<<<dim3(1024, NHEADS), 128, 0, stream>>>(
        x, g1, b1, qkv_self_w, qkv_self_b, attn_mask, rpb_table, rpi, xout);
    k_attn_mut_fb<<<dim3(1024, NHEADS, 2), 64, 0, stream>>>(
        x, g1, b1, qkv_mut_w, qkv_mut_b, pos_bias, attn_mask, xout);
    k_proj_fb<0><<<512, 256, 0, stream>>>(xout, proj_w, proj_b, x, out);
    k_proj_fb<1><<<512, 256, 0, stream>>>(xout, proj_w, proj_b, x, out);
    k_ffn1_fb<<<512, 256, 0, stream>>>(out, g2, b2, fc11_w, fc11_b, fc12_w, fc12_b, hbuf);
    k_ffn2_fb<0><<<512, 256, 0, stream>>>(hbuf, fc2_w, fc2_b, out);
    k_ffn2_fb<1><<<512, 256, 0, stream>>>(hbuf, fc2_w, fc2_b, out);
  }
}